// Round 1
// baseline (1519.665 us; speedup 1.0000x reference)
//
#include <hip/hip_runtime.h>

#define N_ENTITIES 200000
#define N_ITEMS    100000
#define DIM        64
#define N_EDGES    1500000
#define K_EDGES    256
#define K_ITEMS    100
// 1 / (2 * sqrt(32))  (mean over 2 heads of per-head 1/sqrt(Dk))
#define SCALE      0.08838834764831845f

#define CAND_CAP   4096

// ---- monotonic float<->u32 key (order-preserving, total order) ----
__device__ __forceinline__ unsigned fkey(float x) {
    unsigned u = __float_as_uint(x);
    return (u & 0x80000000u) ? ~u : (u | 0x80000000u);
}
__device__ __forceinline__ float funkey(unsigned k) {
    return (k & 0x80000000u) ? __uint_as_float(k & 0x7fffffffu)
                             : __uint_as_float(~k);
}

// ---- init per-entity accumulators ----
__global__ void init_entities(unsigned* __restrict__ segmax, float* __restrict__ denom,
                              float* __restrict__ deg, float* __restrict__ sumnode) {
    int i = blockIdx.x * blockDim.x + threadIdx.x;
    if (i < N_ENTITIES) {
        segmax[i] = 0u;   // key 0 is below every real float key
        denom[i] = 0.f;
        deg[i] = 0.f;
        sumnode[i] = 0.f;
    }
}

// ---- proj = emb @ W_Q : one wave per row, W_Q in LDS ----
__global__ void proj_kernel(const float* __restrict__ emb, const float* __restrict__ W,
                            float* __restrict__ proj) {
    __shared__ float Wl[64 * 64];
    for (int i = threadIdx.x; i < 64 * 64; i += blockDim.x) Wl[i] = W[i];
    __syncthreads();
    int wave = (blockIdx.x * blockDim.x + threadIdx.x) >> 6;
    int lane = threadIdx.x & 63;
    int nw = (gridDim.x * blockDim.x) >> 6;
    for (int row = wave; row < N_ENTITIES; row += nw) {
        float v = emb[row * 64 + lane];
        float acc = 0.f;
#pragma unroll
        for (int k = 0; k < 64; ++k)
            acc += __shfl(v, k, 64) * Wl[k * 64 + lane];
        proj[row * 64 + lane] = acc;
    }
}

// ---- per-edge logits + segmax + deg + sum_by_node, one wave per edge ----
__global__ void edge_pass1(const float* __restrict__ proj, const float* __restrict__ rel,
                           const int* __restrict__ head, const int* __restrict__ tail,
                           const int* __restrict__ etype,
                           float* __restrict__ logits, unsigned* __restrict__ segmax,
                           float* __restrict__ deg, float* __restrict__ sumnode) {
    int wave = (blockIdx.x * blockDim.x + threadIdx.x) >> 6;
    int lane = threadIdx.x & 63;
    int nw = (gridDim.x * blockDim.x) >> 6;
    for (int e = wave; e < N_EDGES; e += nw) {
        int h = head[e], t = tail[e], r = etype[e] - 1;
        float p = proj[h * 64 + lane] * proj[t * 64 + lane] * rel[r * 64 + lane];
#pragma unroll
        for (int off = 32; off > 0; off >>= 1) p += __shfl_xor(p, off, 64);
        if (lane == 0) {
            float lg = p * SCALE;
            logits[e] = lg;
            atomicMax(&segmax[h], fkey(lg));
            atomicAdd(&deg[h], 1.0f);
            atomicAdd(&sumnode[h], lg);
            atomicAdd(&sumnode[t], lg);
        }
    }
}

// ---- denom = segment_sum(exp(logit - segmax[head])) ----
__global__ void edge_pass2(const float* __restrict__ logits, const int* __restrict__ head,
                           const unsigned* __restrict__ segmax, float* __restrict__ denom) {
    int i = blockIdx.x * blockDim.x + threadIdx.x;
    if (i >= N_EDGES) return;
    int h = head[i];
    float ex = __expf(0.f) * expf(logits[i] - funkey(segmax[h]));
    atomicAdd(&denom[h], ex);
}

// ---- score out + gumbel-noised keys ----
__global__ void edge_pass3(const float* __restrict__ logits, const int* __restrict__ head,
                           const unsigned* __restrict__ segmax, const float* __restrict__ denom,
                           const float* __restrict__ deg, const float* __restrict__ noise_u,
                           float* __restrict__ out_scores, unsigned* __restrict__ keys) {
    int i = blockIdx.x * blockDim.x + threadIdx.x;
    if (i >= N_EDGES) return;
    int h = head[i];
    float ex = expf(logits[i] - funkey(segmax[h]));
    float score = ex / denom[h] * deg[h];
    out_scores[i] = score;
    float noise = -logf(-logf(noise_u[i]));
    keys[i] = fkey(score + noise);
}

// ---- item keys from sum_by_node[:N_ITEMS] ----
__global__ void item_keys_kernel(const float* __restrict__ sumnode, unsigned* __restrict__ keys) {
    int i = blockIdx.x * blockDim.x + threadIdx.x;
    if (i < N_ITEMS) keys[i] = fkey(sumnode[i]);
}

// ---- top-k machinery: 2-level 16-bit radix select on keys ----
__global__ void hist_hi_kernel(const unsigned* __restrict__ keys, int n, unsigned* __restrict__ hist) {
    int i = blockIdx.x * blockDim.x + threadIdx.x;
    int stride = gridDim.x * blockDim.x;
    for (; i < n; i += stride) atomicAdd(&hist[keys[i] >> 16], 1u);
}

__global__ void hist_lo_kernel(const unsigned* __restrict__ keys, int n,
                               const unsigned* __restrict__ sel1, unsigned* __restrict__ hist) {
    unsigned hi = sel1[0];
    int i = blockIdx.x * blockDim.x + threadIdx.x;
    int stride = gridDim.x * blockDim.x;
    for (; i < n; i += stride) {
        unsigned k = keys[i];
        if ((k >> 16) == hi) atomicAdd(&hist[k & 0xFFFFu], 1u);
    }
}

// single block, 1024 threads, 65536 bins. out[0]=selected bin, out[1]=count strictly above (cumulative).
__global__ void select_kernel(const unsigned* __restrict__ hist, unsigned K,
                              const unsigned* __restrict__ prev, unsigned* __restrict__ out) {
    __shared__ unsigned cs[1024];
    int t = threadIdx.x;
    unsigned prevAbove = prev ? prev[1] : 0u;
    unsigned Keff = K - prevAbove;
    unsigned s = 0;
    int base = t * 64;
    for (int i = 0; i < 64; ++i) s += hist[base + i];
    cs[t] = s;
    __syncthreads();
    // inclusive suffix sum over chunks (Hillis-Steele)
    for (int off = 1; off < 1024; off <<= 1) {
        unsigned v = cs[t];
        unsigned w = (t + off < 1024) ? cs[t + off] : 0u;
        __syncthreads();
        cs[t] = v + w;
        __syncthreads();
    }
    unsigned incl = cs[t];
    unsigned above = incl - s;
    if (above < Keff && Keff <= incl) {
        unsigned cum = above;
        for (int b = 63; b >= 0; --b) {
            unsigned hb = hist[base + b];
            if (cum + hb >= Keff) {
                out[0] = (unsigned)(base + b);
                out[1] = prevAbove + cum;
                break;
            }
            cum += hb;
        }
    }
}

__global__ void collect_kernel(const unsigned* __restrict__ keys, int n,
                               const unsigned* __restrict__ sel1, const unsigned* __restrict__ sel2,
                               unsigned* __restrict__ counter, unsigned* __restrict__ cand) {
    unsigned T = (sel1[0] << 16) | sel2[0];
    int i = blockIdx.x * blockDim.x + threadIdx.x;
    int stride = gridDim.x * blockDim.x;
    for (; i < n; i += stride) {
        unsigned k = keys[i];
        if (k >= T) {
            unsigned p = atomicAdd(counter, 1u);
            if (p < (unsigned)CAND_CAP) { cand[2 * p] = k; cand[2 * p + 1] = (unsigned)i; }
        }
    }
}

// single block: exact rank among candidates (key desc, index asc), write top K.
__global__ void final_topk_kernel(const unsigned* __restrict__ cand, const unsigned* __restrict__ counter,
                                  int K, float* __restrict__ outv, float* __restrict__ outi) {
    __shared__ unsigned sk[CAND_CAP];
    __shared__ unsigned si[CAND_CAP];
    unsigned m = *counter;
    if (m > (unsigned)CAND_CAP) m = CAND_CAP;
    for (unsigned i = threadIdx.x; i < m; i += blockDim.x) {
        sk[i] = cand[2 * i];
        si[i] = cand[2 * i + 1];
    }
    __syncthreads();
    for (unsigned i = threadIdx.x; i < m; i += blockDim.x) {
        unsigned ki = sk[i], xi = si[i];
        int r = 0;
        for (unsigned j = 0; j < m; ++j) {
            unsigned kj = sk[j];
            if (kj > ki || (kj == ki && si[j] < xi)) r++;
        }
        if (r < K) {
            outv[r] = funkey(ki);
            outi[r] = (float)xi;
        }
    }
}

extern "C" void kernel_launch(void* const* d_in, const int* in_sizes, int n_in,
                              void* d_out, int out_size, void* d_ws, size_t ws_size,
                              hipStream_t stream) {
    (void)in_sizes; (void)n_in; (void)out_size; (void)ws_size;
    const float* emb    = (const float*)d_in[0];
    const float* W      = (const float*)d_in[1];
    const float* rel    = (const float*)d_in[2];
    const float* noise  = (const float*)d_in[3];
    const int*   eidx   = (const int*)d_in[4];
    const int*   etype  = (const int*)d_in[5];
    const int* head = eidx;
    const int* tail = eidx + N_EDGES;

    float* out        = (float*)d_out;
    float* out_scores = out;                                   // [E]
    float* out_topkv  = out + N_EDGES;                         // [256]
    float* out_topki  = out + N_EDGES + K_EDGES;               // [256] (as float)
    float* out_itemv  = out + N_EDGES + 2 * K_EDGES;           // [100]
    float* out_itemi  = out + N_EDGES + 2 * K_EDGES + K_ITEMS; // [100] (as float)

    float* ws = (float*)d_ws;
    size_t o = 0;
    float*    proj    = ws + o;              o += (size_t)N_ENTITIES * DIM;
    float*    logits  = ws + o;              o += N_EDGES;
    unsigned* keysE   = (unsigned*)(ws + o); o += N_EDGES;
    unsigned* segmax  = (unsigned*)(ws + o); o += N_ENTITIES;
    float*    denom   = ws + o;              o += N_ENTITIES;
    float*    deg     = ws + o;              o += N_ENTITIES;
    float*    sumnode = ws + o;              o += N_ENTITIES;
    unsigned* keysI   = (unsigned*)(ws + o); o += N_ITEMS;
    unsigned* hist1   = (unsigned*)(ws + o); o += 65536;
    unsigned* hist2   = (unsigned*)(ws + o); o += 65536;
    unsigned* counter = (unsigned*)(ws + o); o += 1;   // contiguous after hist2 -> one memset
    unsigned* sel1    = (unsigned*)(ws + o); o += 2;
    unsigned* sel2    = (unsigned*)(ws + o); o += 2;
    unsigned* cand    = (unsigned*)(ws + o); o += 2 * CAND_CAP;

    // 1. init accumulators
    hipLaunchKernelGGL(init_entities, dim3((N_ENTITIES + 255) / 256), dim3(256), 0, stream,
                       segmax, denom, deg, sumnode);
    // 2. projection
    hipLaunchKernelGGL(proj_kernel, dim3(12800), dim3(256), 0, stream, emb, W, proj);
    // 3. logits + segmax + deg + sum_by_node
    hipLaunchKernelGGL(edge_pass1, dim3((N_EDGES + 3) / 4), dim3(256), 0, stream,
                       proj, rel, head, tail, etype, logits, segmax, deg, sumnode);
    // 4. softmax denominators
    hipLaunchKernelGGL(edge_pass2, dim3((N_EDGES + 255) / 256), dim3(256), 0, stream,
                       logits, head, segmax, denom);
    // 5. scores + noisy keys
    hipLaunchKernelGGL(edge_pass3, dim3((N_EDGES + 255) / 256), dim3(256), 0, stream,
                       logits, head, segmax, denom, deg, noise, out_scores, keysE);

    // ---- edge top-256 ----
    hipMemsetAsync(hist1, 0, (size_t)(65536 * 2 + 1) * 4, stream);
    hipLaunchKernelGGL(hist_hi_kernel, dim3(1024), dim3(256), 0, stream, keysE, N_EDGES, hist1);
    hipLaunchKernelGGL(select_kernel, dim3(1), dim3(1024), 0, stream, hist1, (unsigned)K_EDGES,
                       (const unsigned*)nullptr, sel1);
    hipLaunchKernelGGL(hist_lo_kernel, dim3(1024), dim3(256), 0, stream, keysE, N_EDGES, sel1, hist2);
    hipLaunchKernelGGL(select_kernel, dim3(1), dim3(1024), 0, stream, hist2, (unsigned)K_EDGES,
                       (const unsigned*)sel1, sel2);
    hipLaunchKernelGGL(collect_kernel, dim3(1024), dim3(256), 0, stream, keysE, N_EDGES,
                       sel1, sel2, counter, cand);
    hipLaunchKernelGGL(final_topk_kernel, dim3(1), dim3(1024), 0, stream, cand, counter,
                       K_EDGES, out_topkv, out_topki);

    // ---- item top-100 ----
    hipLaunchKernelGGL(item_keys_kernel, dim3((N_ITEMS + 255) / 256), dim3(256), 0, stream,
                       sumnode, keysI);
    hipMemsetAsync(hist1, 0, (size_t)(65536 * 2 + 1) * 4, stream);
    hipLaunchKernelGGL(hist_hi_kernel, dim3(512), dim3(256), 0, stream, keysI, N_ITEMS, hist1);
    hipLaunchKernelGGL(select_kernel, dim3(1), dim3(1024), 0, stream, hist1, (unsigned)K_ITEMS,
                       (const unsigned*)nullptr, sel1);
    hipLaunchKernelGGL(hist_lo_kernel, dim3(512), dim3(256), 0, stream, keysI, N_ITEMS, sel1, hist2);
    hipLaunchKernelGGL(select_kernel, dim3(1), dim3(1024), 0, stream, hist2, (unsigned)K_ITEMS,
                       (const unsigned*)sel1, sel2);
    hipLaunchKernelGGL(collect_kernel, dim3(512), dim3(256), 0, stream, keysI, N_ITEMS,
                       sel1, sel2, counter, cand);
    hipLaunchKernelGGL(final_topk_kernel, dim3(1), dim3(1024), 0, stream, cand, counter,
                       K_ITEMS, out_itemv, out_itemi);
}

// Round 2
// 948.859 us; speedup vs baseline: 1.6016x; 1.6016x over previous
//
#include <hip/hip_runtime.h>

#define N_ENTITIES 200000
#define N_ITEMS    100000
#define DIM        64
#define N_EDGES    1500000
#define K_EDGES    256
#define K_ITEMS    100
// 1 / (2 * sqrt(32))  (mean over 2 heads of per-head 1/sqrt(Dk))
#define SCALE      0.08838834764831845f

#define CAND_CAP   4096

// ---- monotonic float<->u32 key (order-preserving, total order) ----
__device__ __forceinline__ unsigned fkey(float x) {
    unsigned u = __float_as_uint(x);
    return (u & 0x80000000u) ? ~u : (u | 0x80000000u);
}
__device__ __forceinline__ float funkey(unsigned k) {
    return (k & 0x80000000u) ? __uint_as_float(k & 0x7fffffffu)
                             : __uint_as_float(~k);
}

// ---- init per-entity accumulators ----
__global__ void init_entities(unsigned* __restrict__ segmax, float* __restrict__ denom,
                              float* __restrict__ deg, float* __restrict__ sumnode) {
    int i = blockIdx.x * blockDim.x + threadIdx.x;
    if (i < N_ENTITIES) {
        segmax[i] = 0u;   // key 0 is below every real float key
        denom[i] = 0.f;
        deg[i] = 0.f;
        sumnode[i] = 0.f;
    }
}

// ---- proj = emb @ W_Q : one wave per row, W_Q in LDS ----
__global__ void proj_kernel(const float* __restrict__ emb, const float* __restrict__ W,
                            float* __restrict__ proj) {
    __shared__ float Wl[64 * 64];
    for (int i = threadIdx.x; i < 64 * 64; i += blockDim.x) Wl[i] = W[i];
    __syncthreads();
    int wave = (blockIdx.x * blockDim.x + threadIdx.x) >> 6;
    int lane = threadIdx.x & 63;
    int nw = (gridDim.x * blockDim.x) >> 6;
    for (int row = wave; row < N_ENTITIES; row += nw) {
        float v = emb[row * 64 + lane];
        float acc = 0.f;
#pragma unroll
        for (int k = 0; k < 64; ++k)
            acc += __shfl(v, k, 64) * Wl[k * 64 + lane];
        proj[row * 64 + lane] = acc;
    }
}

// ---- per-edge logits + segmax + deg + sum_by_node, one wave per edge ----
__global__ void edge_pass1(const float* __restrict__ proj, const float* __restrict__ rel,
                           const int* __restrict__ head, const int* __restrict__ tail,
                           const int* __restrict__ etype,
                           float* __restrict__ logits, unsigned* __restrict__ segmax,
                           float* __restrict__ deg, float* __restrict__ sumnode) {
    int wave = (blockIdx.x * blockDim.x + threadIdx.x) >> 6;
    int lane = threadIdx.x & 63;
    int nw = (gridDim.x * blockDim.x) >> 6;
    for (int e = wave; e < N_EDGES; e += nw) {
        int h = head[e], t = tail[e], r = etype[e] - 1;
        float p = proj[h * 64 + lane] * proj[t * 64 + lane] * rel[r * 64 + lane];
#pragma unroll
        for (int off = 32; off > 0; off >>= 1) p += __shfl_xor(p, off, 64);
        if (lane == 0) {
            float lg = p * SCALE;
            logits[e] = lg;
            atomicMax(&segmax[h], fkey(lg));
            atomicAdd(&deg[h], 1.0f);
            atomicAdd(&sumnode[h], lg);
            atomicAdd(&sumnode[t], lg);
        }
    }
}

// ---- denom = segment_sum(exp(logit - segmax[head])) ----
__global__ void edge_pass2(const float* __restrict__ logits, const int* __restrict__ head,
                           const unsigned* __restrict__ segmax, float* __restrict__ denom) {
    int i = blockIdx.x * blockDim.x + threadIdx.x;
    if (i >= N_EDGES) return;
    int h = head[i];
    float ex = expf(logits[i] - funkey(segmax[h]));
    atomicAdd(&denom[h], ex);
}

// ---- score out + gumbel-noised keys ----
__global__ void edge_pass3(const float* __restrict__ logits, const int* __restrict__ head,
                           const unsigned* __restrict__ segmax, const float* __restrict__ denom,
                           const float* __restrict__ deg, const float* __restrict__ noise_u,
                           float* __restrict__ out_scores, unsigned* __restrict__ keys) {
    int i = blockIdx.x * blockDim.x + threadIdx.x;
    if (i >= N_EDGES) return;
    int h = head[i];
    float ex = expf(logits[i] - funkey(segmax[h]));
    float score = ex / denom[h] * deg[h];
    out_scores[i] = score;
    float noise = -logf(-logf(noise_u[i]));
    keys[i] = fkey(score + noise);
}

// ---- item keys from sum_by_node[:N_ITEMS] ----
__global__ void item_keys_kernel(const float* __restrict__ sumnode, unsigned* __restrict__ keys) {
    int i = blockIdx.x * blockDim.x + threadIdx.x;
    if (i < N_ITEMS) keys[i] = fkey(sumnode[i]);
}

// ---- 8-bit-digit radix pass: wave-aggregated LDS-private histogram ----
// bin = (key >> shift) & 0xFF among keys whose higher bits match prefix
// (prevSel==nullptr -> no prefix filter).
__global__ void hist8_kernel(const unsigned* __restrict__ keys, int n, int shift,
                             const unsigned* __restrict__ prevSel, unsigned* __restrict__ hist) {
    __shared__ unsigned h[256];
    for (int i = threadIdx.x; i < 256; i += blockDim.x) h[i] = 0;
    __syncthreads();
    const bool hasPrefix = (prevSel != nullptr);
    const unsigned prefix = hasPrefix ? prevSel[0] : 0u;
    const int lane = threadIdx.x & 63;
    const int stride = gridDim.x * blockDim.x;
    for (int idx = blockIdx.x * blockDim.x + threadIdx.x; idx - lane < n; idx += stride) {
        bool valid = (idx < n);
        unsigned bin = 0;
        if (valid) {
            unsigned k = keys[idx];
            // ((k>>shift)>>8) avoids UB when shift==24
            if (hasPrefix && (((k >> shift) >> 8) != prefix)) valid = false;
            bin = (k >> shift) & 0xFFu;
        }
        // wave-aggregated commit: one LDS atomic per distinct bin per wave
        bool need = valid;
        for (;;) {
            unsigned long long mask = __ballot(need);
            if (mask == 0ull) break;
            int leader = __ffsll(mask) - 1;
            unsigned lbin = __shfl(bin, leader, 64);
            bool same = need && (bin == lbin);
            unsigned long long grp = __ballot(same);
            if (lane == leader) atomicAdd(&h[lbin], (unsigned)__popcll(grp));
            need = need && !same;
        }
    }
    __syncthreads();
    for (int i = threadIdx.x; i < 256; i += blockDim.x) {
        unsigned v = h[i];
        if (v) atomicAdd(&hist[i], v);
    }
}

// single block, 256 threads. out[0] = (prevPrefix<<8)|bin, out[1] = cumulative count strictly above.
__global__ void select256_kernel(const unsigned* __restrict__ hist, unsigned K,
                                 const unsigned* __restrict__ prev, unsigned* __restrict__ out) {
    __shared__ unsigned h[256];
    int t = threadIdx.x;
    h[t] = hist[t];
    __syncthreads();
    if (t == 0) {
        unsigned prevPrefix = prev ? prev[0] : 0u;
        unsigned prevAbove = prev ? prev[1] : 0u;
        unsigned Keff = K - prevAbove;
        unsigned cum = 0;
        int b = 255;
        for (; b > 0; --b) {
            unsigned hb = h[b];
            if (cum + hb >= Keff) break;
            cum += hb;
        }
        out[0] = (prevPrefix << 8) | (unsigned)b;
        out[1] = prevAbove + cum;
    }
}

// collect all keys >= (sel[0] << 8)  (24-bit prefix threshold)
__global__ void collect_kernel(const unsigned* __restrict__ keys, int n,
                               const unsigned* __restrict__ sel,
                               unsigned* __restrict__ counter, unsigned* __restrict__ cand) {
    unsigned T = sel[0] << 8;
    int i = blockIdx.x * blockDim.x + threadIdx.x;
    int stride = gridDim.x * blockDim.x;
    for (; i < n; i += stride) {
        unsigned k = keys[i];
        if (k >= T) {
            unsigned p = atomicAdd(counter, 1u);
            if (p < (unsigned)CAND_CAP) { cand[2 * p] = k; cand[2 * p + 1] = (unsigned)i; }
        }
    }
}

// single block: exact rank among candidates (key desc, index asc), write top K.
__global__ void final_topk_kernel(const unsigned* __restrict__ cand, const unsigned* __restrict__ counter,
                                  int K, float* __restrict__ outv, float* __restrict__ outi) {
    __shared__ unsigned sk[CAND_CAP];
    __shared__ unsigned si[CAND_CAP];
    unsigned m = *counter;
    if (m > (unsigned)CAND_CAP) m = CAND_CAP;
    for (unsigned i = threadIdx.x; i < m; i += blockDim.x) {
        sk[i] = cand[2 * i];
        si[i] = cand[2 * i + 1];
    }
    __syncthreads();
    for (unsigned i = threadIdx.x; i < m; i += blockDim.x) {
        unsigned ki = sk[i], xi = si[i];
        int r = 0;
        for (unsigned j = 0; j < m; ++j) {
            unsigned kj = sk[j];
            if (kj > ki || (kj == ki && si[j] < xi)) r++;
        }
        if (r < K) {
            outv[r] = funkey(ki);
            outi[r] = (float)xi;
        }
    }
}

static void run_topk(const unsigned* keys, int n, unsigned K, int nblocks,
                     unsigned* histA, unsigned* histB, unsigned* histC,
                     unsigned* selA, unsigned* selB, unsigned* selC,
                     unsigned* counter, unsigned* cand,
                     float* outv, float* outi, hipStream_t stream) {
    hipLaunchKernelGGL(hist8_kernel, dim3(nblocks), dim3(256), 0, stream,
                       keys, n, 24, (const unsigned*)nullptr, histA);
    hipLaunchKernelGGL(select256_kernel, dim3(1), dim3(256), 0, stream,
                       histA, K, (const unsigned*)nullptr, selA);
    hipLaunchKernelGGL(hist8_kernel, dim3(nblocks), dim3(256), 0, stream,
                       keys, n, 16, selA, histB);
    hipLaunchKernelGGL(select256_kernel, dim3(1), dim3(256), 0, stream,
                       histB, K, selA, selB);
    hipLaunchKernelGGL(hist8_kernel, dim3(nblocks), dim3(256), 0, stream,
                       keys, n, 8, selB, histC);
    hipLaunchKernelGGL(select256_kernel, dim3(1), dim3(256), 0, stream,
                       histC, K, selB, selC);
    hipLaunchKernelGGL(collect_kernel, dim3(nblocks), dim3(256), 0, stream,
                       keys, n, selC, counter, cand);
    hipLaunchKernelGGL(final_topk_kernel, dim3(1), dim3(1024), 0, stream,
                       cand, counter, (int)K, outv, outi);
}

extern "C" void kernel_launch(void* const* d_in, const int* in_sizes, int n_in,
                              void* d_out, int out_size, void* d_ws, size_t ws_size,
                              hipStream_t stream) {
    (void)in_sizes; (void)n_in; (void)out_size; (void)ws_size;
    const float* emb    = (const float*)d_in[0];
    const float* W      = (const float*)d_in[1];
    const float* rel    = (const float*)d_in[2];
    const float* noise  = (const float*)d_in[3];
    const int*   eidx   = (const int*)d_in[4];
    const int*   etype  = (const int*)d_in[5];
    const int* head = eidx;
    const int* tail = eidx + N_EDGES;

    float* out        = (float*)d_out;
    float* out_scores = out;                                   // [E]
    float* out_topkv  = out + N_EDGES;                         // [256]
    float* out_topki  = out + N_EDGES + K_EDGES;               // [256] (as float)
    float* out_itemv  = out + N_EDGES + 2 * K_EDGES;           // [100]
    float* out_itemi  = out + N_EDGES + 2 * K_EDGES + K_ITEMS; // [100] (as float)

    float* ws = (float*)d_ws;
    size_t o = 0;
    float*    proj    = ws + o;              o += (size_t)N_ENTITIES * DIM;
    float*    logits  = ws + o;              o += N_EDGES;
    unsigned* keysE   = (unsigned*)(ws + o); o += N_EDGES;
    unsigned* segmax  = (unsigned*)(ws + o); o += N_ENTITIES;
    float*    denom   = ws + o;              o += N_ENTITIES;
    float*    deg     = ws + o;              o += N_ENTITIES;
    float*    sumnode = ws + o;              o += N_ENTITIES;
    unsigned* keysI   = (unsigned*)(ws + o); o += N_ITEMS;
    // contiguous block so one small memset clears everything:
    unsigned* histA   = (unsigned*)(ws + o); o += 256;
    unsigned* histB   = (unsigned*)(ws + o); o += 256;
    unsigned* histC   = (unsigned*)(ws + o); o += 256;
    unsigned* counter = (unsigned*)(ws + o); o += 1;
    unsigned* selA    = (unsigned*)(ws + o); o += 2;
    unsigned* selB    = (unsigned*)(ws + o); o += 2;
    unsigned* selC    = (unsigned*)(ws + o); o += 2;
    unsigned* cand    = (unsigned*)(ws + o); o += 2 * CAND_CAP;

    // 1. init accumulators
    hipLaunchKernelGGL(init_entities, dim3((N_ENTITIES + 255) / 256), dim3(256), 0, stream,
                       segmax, denom, deg, sumnode);
    // 2. projection
    hipLaunchKernelGGL(proj_kernel, dim3(12800), dim3(256), 0, stream, emb, W, proj);
    // 3. logits + segmax + deg + sum_by_node
    hipLaunchKernelGGL(edge_pass1, dim3((N_EDGES + 3) / 4), dim3(256), 0, stream,
                       proj, rel, head, tail, etype, logits, segmax, deg, sumnode);
    // 4. softmax denominators
    hipLaunchKernelGGL(edge_pass2, dim3((N_EDGES + 255) / 256), dim3(256), 0, stream,
                       logits, head, segmax, denom);
    // 5. scores + noisy keys
    hipLaunchKernelGGL(edge_pass3, dim3((N_EDGES + 255) / 256), dim3(256), 0, stream,
                       logits, head, segmax, denom, deg, noise, out_scores, keysE);

    // ---- edge top-256 ----
    hipMemsetAsync(histA, 0, (size_t)(3 * 256 + 1) * 4, stream);
    run_topk(keysE, N_EDGES, K_EDGES, 512, histA, histB, histC, selA, selB, selC,
             counter, cand, out_topkv, out_topki, stream);

    // ---- item top-100 ----
    hipLaunchKernelGGL(item_keys_kernel, dim3((N_ITEMS + 255) / 256), dim3(256), 0, stream,
                       sumnode, keysI);
    hipMemsetAsync(histA, 0, (size_t)(3 * 256 + 1) * 4, stream);
    run_topk(keysI, N_ITEMS, K_ITEMS, 256, histA, histB, histC, selA, selB, selC,
             counter, cand, out_itemv, out_itemi, stream);
}

// Round 3
// 591.951 us; speedup vs baseline: 2.5672x; 1.6029x over previous
//
#include <hip/hip_runtime.h>

#define N_ENTITIES 200000
#define N_ITEMS    100000
#define DIM        64
#define N_EDGES    1500000
#define K_EDGES    256
#define K_ITEMS    100
// 1 / (2 * sqrt(32))  (mean over 2 heads of per-head 1/sqrt(Dk))
#define SCALE      0.08838834764831845f

#define CAND_CAP   4096

// ---- monotonic float<->u32 key (order-preserving, total order) ----
__device__ __forceinline__ unsigned fkey(float x) {
    unsigned u = __float_as_uint(x);
    return (u & 0x80000000u) ? ~u : (u | 0x80000000u);
}
__device__ __forceinline__ float funkey(unsigned k) {
    return (k & 0x80000000u) ? __uint_as_float(k & 0x7fffffffu)
                             : __uint_as_float(~k);
}

// ---- proj = emb @ W_Q ----
// Block = 256 threads = (q in [0,4)) x (c in [0,64)). Each block does 16 rows.
// Thread holds W[q*16+j][c] (16 regs). emb row values are wave-uniform ->
// scalar loads through K$. 256 FMA/thread, LDS only for 4-way k-partial reduce.
__global__ __launch_bounds__(256) void proj_kernel(const float* __restrict__ emb,
                                                   const float* __restrict__ W,
                                                   float* __restrict__ proj) {
    __shared__ float part[4][16][64];
    const int t = threadIdx.x;
    const int c = t & 63;
    const int q = __builtin_amdgcn_readfirstlane(t >> 6);

    float Wreg[16];
#pragma unroll
    for (int j = 0; j < 16; ++j) Wreg[j] = W[(q * 16 + j) * 64 + c];

    const int base = blockIdx.x * 16;   // 200000 = 12500 * 16, exact
    const float* erow = emb + (size_t)base * 64 + q * 16;

    float acc[16];
#pragma unroll
    for (int r = 0; r < 16; ++r) acc[r] = 0.f;
#pragma unroll
    for (int r = 0; r < 16; ++r) {
#pragma unroll
        for (int j = 0; j < 16; ++j)
            acc[r] += erow[r * 64 + j] * Wreg[j];
    }
#pragma unroll
    for (int r = 0; r < 16; ++r) part[q][r][c] = acc[r];
    __syncthreads();
#pragma unroll
    for (int it = 0; it < 4; ++it) {
        int oi = t + it * 256;
        int r = oi >> 6, cc = oi & 63;
        float s = part[0][r][cc] + part[1][r][cc] + part[2][r][cc] + part[3][r][cc];
        proj[(size_t)(base + r) * 64 + cc] = s;
    }
}

// ---- fused edge pass: logits + denom(exp) + deg + sum_by_node ----
// 4 edges per wave, 16 lanes per edge, float4 fragments.
// No segment-max: logits are O(0.1), exp(l)/sum(exp(l)) is exactly the same
// math as the max-shifted version.
__global__ __launch_bounds__(256) void edge_fused(const float4* __restrict__ proj4,
                                                  const float4* __restrict__ rel4,
                                                  const int* __restrict__ head,
                                                  const int* __restrict__ tail,
                                                  const int* __restrict__ etype,
                                                  float* __restrict__ logits,
                                                  float* __restrict__ nd,      // [2*N_ENTITIES]: {denom, deg}
                                                  float* __restrict__ sumnode) {
    int gid = blockIdx.x * blockDim.x + threadIdx.x;
    int wave = gid >> 6;
    int lane = threadIdx.x & 63;
    int sl = lane & 15;
    int e = wave * 4 + (lane >> 4);
    if (e >= N_EDGES) return;
    int h = head[e], t = tail[e], r = etype[e] - 1;
    float4 a = proj4[(size_t)h * 16 + sl];
    float4 b = proj4[(size_t)t * 16 + sl];
    float4 cr = rel4[(size_t)r * 16 + sl];
    float s = a.x * b.x * cr.x + a.y * b.y * cr.y + a.z * b.z * cr.z + a.w * b.w * cr.w;
    s += __shfl_xor(s, 1, 64);
    s += __shfl_xor(s, 2, 64);
    s += __shfl_xor(s, 4, 64);
    s += __shfl_xor(s, 8, 64);
    if (sl == 0) {
        float lg = s * SCALE;
        logits[e] = lg;
        atomicAdd(&nd[2 * h], __expf(lg));
        atomicAdd(&nd[2 * h + 1], 1.0f);
        atomicAdd(&sumnode[h], lg);
        atomicAdd(&sumnode[t], lg);
    }
}

// ---- scores + gumbel keys + item keys ----
__global__ void edge_pass3(const float* __restrict__ logits, const int* __restrict__ head,
                           const float2* __restrict__ nd, const float* __restrict__ noise_u,
                           const float* __restrict__ sumnode,
                           float* __restrict__ out_scores, unsigned* __restrict__ keysE,
                           unsigned* __restrict__ keysI) {
    int i = blockIdx.x * blockDim.x + threadIdx.x;
    if (i >= N_EDGES) return;
    float lg = logits[i];
    float2 dd = nd[head[i]];
    float score = __expf(lg) / dd.x * dd.y;
    out_scores[i] = score;
    float noise = -logf(-logf(noise_u[i]));   // library logf: accurate near u->1
    keysE[i] = fkey(score + noise);
    if (i < N_ITEMS) keysI[i] = fkey(sumnode[i]);
}

// ---- 8-bit-digit radix pass: wave-aggregated LDS-private histogram ----
__global__ void hist8_kernel(const unsigned* __restrict__ keys, int n, int shift,
                             const unsigned* __restrict__ prevSel, unsigned* __restrict__ hist) {
    __shared__ unsigned h[256];
    for (int i = threadIdx.x; i < 256; i += blockDim.x) h[i] = 0;
    __syncthreads();
    const bool hasPrefix = (prevSel != nullptr);
    const unsigned prefix = hasPrefix ? prevSel[0] : 0u;
    const int lane = threadIdx.x & 63;
    const int stride = gridDim.x * blockDim.x;
    for (int idx = blockIdx.x * blockDim.x + threadIdx.x; idx - lane < n; idx += stride) {
        bool valid = (idx < n);
        unsigned bin = 0;
        if (valid) {
            unsigned k = keys[idx];
            if (hasPrefix && (((k >> shift) >> 8) != prefix)) valid = false;
            bin = (k >> shift) & 0xFFu;
        }
        bool need = valid;
        for (;;) {
            unsigned long long mask = __ballot(need);
            if (mask == 0ull) break;
            int leader = __ffsll(mask) - 1;
            unsigned lbin = __shfl(bin, leader, 64);
            bool same = need && (bin == lbin);
            unsigned long long grp = __ballot(same);
            if (lane == leader) atomicAdd(&h[lbin], (unsigned)__popcll(grp));
            need = need && !same;
        }
    }
    __syncthreads();
    for (int i = threadIdx.x; i < 256; i += blockDim.x) {
        unsigned v = h[i];
        if (v) atomicAdd(&hist[i], v);
    }
}

// single block, 256 threads. out[0]=(prevPrefix<<8)|bin, out[1]=count strictly above.
__global__ void select256_kernel(const unsigned* __restrict__ hist, unsigned K,
                                 const unsigned* __restrict__ prev, unsigned* __restrict__ out) {
    __shared__ unsigned h[256];
    int t = threadIdx.x;
    h[t] = hist[t];
    __syncthreads();
    if (t == 0) {
        unsigned prevPrefix = prev ? prev[0] : 0u;
        unsigned prevAbove = prev ? prev[1] : 0u;
        unsigned Keff = K - prevAbove;
        unsigned cum = 0;
        int b = 255;
        for (; b > 0; --b) {
            unsigned hb = h[b];
            if (cum + hb >= Keff) break;
            cum += hb;
        }
        out[0] = (prevPrefix << 8) | (unsigned)b;
        out[1] = prevAbove + cum;
    }
}

// collect all keys >= (sel[0] << 8)
__global__ void collect_kernel(const unsigned* __restrict__ keys, int n,
                               const unsigned* __restrict__ sel,
                               unsigned* __restrict__ counter, unsigned* __restrict__ cand) {
    unsigned T = sel[0] << 8;
    int i = blockIdx.x * blockDim.x + threadIdx.x;
    int stride = gridDim.x * blockDim.x;
    for (; i < n; i += stride) {
        unsigned k = keys[i];
        if (k >= T) {
            unsigned p = atomicAdd(counter, 1u);
            if (p < (unsigned)CAND_CAP) { cand[2 * p] = k; cand[2 * p + 1] = (unsigned)i; }
        }
    }
}

// single block: exact rank among candidates (key desc, index asc), write top K.
__global__ void final_topk_kernel(const unsigned* __restrict__ cand, const unsigned* __restrict__ counter,
                                  int K, float* __restrict__ outv, float* __restrict__ outi) {
    __shared__ unsigned sk[CAND_CAP];
    __shared__ unsigned si[CAND_CAP];
    unsigned m = *counter;
    if (m > (unsigned)CAND_CAP) m = CAND_CAP;
    for (unsigned i = threadIdx.x; i < m; i += blockDim.x) {
        sk[i] = cand[2 * i];
        si[i] = cand[2 * i + 1];
    }
    __syncthreads();
    for (unsigned i = threadIdx.x; i < m; i += blockDim.x) {
        unsigned ki = sk[i], xi = si[i];
        int r = 0;
        for (unsigned j = 0; j < m; ++j) {
            unsigned kj = sk[j];
            if (kj > ki || (kj == ki && si[j] < xi)) r++;
        }
        if (r < K) {
            outv[r] = funkey(ki);
            outi[r] = (float)xi;
        }
    }
}

static void run_topk(const unsigned* keys, int n, unsigned K, int nblocks,
                     unsigned* histA, unsigned* histB, unsigned* histC,
                     unsigned* selA, unsigned* selB, unsigned* selC,
                     unsigned* counter, unsigned* cand,
                     float* outv, float* outi, hipStream_t stream) {
    hipLaunchKernelGGL(hist8_kernel, dim3(nblocks), dim3(256), 0, stream,
                       keys, n, 24, (const unsigned*)nullptr, histA);
    hipLaunchKernelGGL(select256_kernel, dim3(1), dim3(256), 0, stream,
                       histA, K, (const unsigned*)nullptr, selA);
    hipLaunchKernelGGL(hist8_kernel, dim3(nblocks), dim3(256), 0, stream,
                       keys, n, 16, selA, histB);
    hipLaunchKernelGGL(select256_kernel, dim3(1), dim3(256), 0, stream,
                       histB, K, selA, selB);
    hipLaunchKernelGGL(hist8_kernel, dim3(nblocks), dim3(256), 0, stream,
                       keys, n, 8, selB, histC);
    hipLaunchKernelGGL(select256_kernel, dim3(1), dim3(256), 0, stream,
                       histC, K, selB, selC);
    hipLaunchKernelGGL(collect_kernel, dim3(nblocks), dim3(256), 0, stream,
                       keys, n, selC, counter, cand);
    hipLaunchKernelGGL(final_topk_kernel, dim3(1), dim3(1024), 0, stream,
                       cand, counter, (int)K, outv, outi);
}

extern "C" void kernel_launch(void* const* d_in, const int* in_sizes, int n_in,
                              void* d_out, int out_size, void* d_ws, size_t ws_size,
                              hipStream_t stream) {
    (void)in_sizes; (void)n_in; (void)out_size; (void)ws_size;
    const float* emb    = (const float*)d_in[0];
    const float* W      = (const float*)d_in[1];
    const float* rel    = (const float*)d_in[2];
    const float* noise  = (const float*)d_in[3];
    const int*   eidx   = (const int*)d_in[4];
    const int*   etype  = (const int*)d_in[5];
    const int* head = eidx;
    const int* tail = eidx + N_EDGES;

    float* out        = (float*)d_out;
    float* out_scores = out;                                   // [E]
    float* out_topkv  = out + N_EDGES;                         // [256]
    float* out_topki  = out + N_EDGES + K_EDGES;               // [256] (as float)
    float* out_itemv  = out + N_EDGES + 2 * K_EDGES;           // [100]
    float* out_itemi  = out + N_EDGES + 2 * K_EDGES + K_ITEMS; // [100] (as float)

    float* ws = (float*)d_ws;
    size_t o = 0;
    float*    proj    = ws + o;              o += (size_t)N_ENTITIES * DIM;
    float*    logits  = ws + o;              o += N_EDGES;
    unsigned* keysE   = (unsigned*)(ws + o); o += N_EDGES;
    float*    nd      = ws + o;              o += 2 * N_ENTITIES;  // {denom,deg} interleaved
    float*    sumnode = ws + o;              o += N_ENTITIES;      // contiguous with nd -> one memset
    unsigned* keysI   = (unsigned*)(ws + o); o += N_ITEMS;
    unsigned* histA   = (unsigned*)(ws + o); o += 256;
    unsigned* histB   = (unsigned*)(ws + o); o += 256;
    unsigned* histC   = (unsigned*)(ws + o); o += 256;
    unsigned* counter = (unsigned*)(ws + o); o += 1;
    unsigned* selA    = (unsigned*)(ws + o); o += 2;
    unsigned* selB    = (unsigned*)(ws + o); o += 2;
    unsigned* selC    = (unsigned*)(ws + o); o += 2;
    unsigned* cand    = (unsigned*)(ws + o); o += 2 * CAND_CAP;

    // 1. zero accumulators (denom/deg/sumnode all zero bit-patterns)
    hipMemsetAsync(nd, 0, (size_t)(3 * N_ENTITIES) * 4, stream);
    // 2. projection (200000/16 = 12500 blocks, exact)
    hipLaunchKernelGGL(proj_kernel, dim3(12500), dim3(256), 0, stream, emb, W, proj);
    // 3. fused: logits + denom + deg + sum_by_node (4 edges/wave)
    hipLaunchKernelGGL(edge_fused, dim3((N_EDGES / 4 + 3) / 4), dim3(256), 0, stream,
                       (const float4*)proj, (const float4*)rel, head, tail, etype,
                       logits, nd, sumnode);
    // 4. scores + noisy edge keys + item keys
    hipLaunchKernelGGL(edge_pass3, dim3((N_EDGES + 255) / 256), dim3(256), 0, stream,
                       logits, head, (const float2*)nd, noise, sumnode,
                       out_scores, keysE, keysI);

    // ---- edge top-256 ----
    hipMemsetAsync(histA, 0, (size_t)(3 * 256 + 1) * 4, stream);
    run_topk(keysE, N_EDGES, K_EDGES, 512, histA, histB, histC, selA, selB, selC,
             counter, cand, out_topkv, out_topki, stream);

    // ---- item top-100 ----
    hipMemsetAsync(histA, 0, (size_t)(3 * 256 + 1) * 4, stream);
    run_topk(keysI, N_ITEMS, K_ITEMS, 256, histA, histB, histC, selA, selB, selC,
             counter, cand, out_itemv, out_itemi, stream);
}